// Round 15
// baseline (352.294 us; speedup 1.0000x reference)
//
#include <hip/hip_runtime.h>
#include <math.h>

constexpr int N = 50000;   // nodes
constexpr int E = 800000;  // edges (without self-loops)
constexpr int F = 128;     // features / hidden
constexpr int G = 256;     // graphs
constexpr int T = 4;       // tasks

constexpr int BSH   = 5;                         // 32 nodes per bucket
constexpr int BNODES= 1 << BSH;
constexpr int NBUCK = (N + BNODES - 1) / BNODES; // 1563
constexpr int CHUNK = 2048;                      // edges per partition block (391 blocks: full-chip)
constexpr int NCHUNK= (E + CHUNK - 1) / CHUNK;   // 391
constexpr int SSH   = 13;                        // src-slice shift: 8192-node slices (0..6)

// k_pre block-range layout
constexpr int WC_BLKS  = (F * F + 255) / 256;    // 64
constexpr int SUM_BLKS = (G * F + 255) / 256;    // 128
constexpr int PRE_H0   = 2 * WC_BLKS + 1;        // 129 (hist chunks)
constexpr int PRE_SUM0 = PRE_H0 + NCHUNK;        // 520
constexpr int PRE_BLKS = PRE_SUM0 + SUM_BLKS;    // 648

constexpr int GB1 = (N + 63) / 64;               // 782 gemm blocks
constexpr int AGB = N / 16;                      // 3125 fused agg+gemm blocks

constexpr int POOL_RUN = 256;                    // nodes per pool group
constexpr int NPGRP = (N + POOL_RUN - 1) / POOL_RUN;  // 196

typedef __attribute__((ext_vector_type(8))) short short8;
typedef __attribute__((ext_vector_type(4))) float floatx4;

// bf16 <-> fp32 helpers (RNE on pack; values are finite)
__device__ inline float bf2f(unsigned short u) {
    union { unsigned int i; float f; } v;
    v.i = ((unsigned int)u) << 16;
    return v.f;
}
__device__ inline unsigned short f2bf(float f) {
    union { float f; unsigned int i; } v;
    v.f = f;
    unsigned int r = v.i + 0x7FFF + ((v.i >> 16) & 1);
    return (unsigned short)(r >> 16);
}
__device__ inline unsigned int pack2bf(float a, float b) {
    return (unsigned int)f2bf(a) | ((unsigned int)f2bf(b) << 16);
}

// pack W (fp32) -> MFMA-B-fragment order, hi/lo bf16 split
__device__ inline void wcast_one(const float* __restrict__ W,
                                 unsigned short* __restrict__ Whi,
                                 unsigned short* __restrict__ Wlo, int i) {
    if (i >= F * F) return;
    int k = i >> 7, n = i & 127;
    float w = W[i];
    unsigned short hi = f2bf(w);
    unsigned short lo = f2bf(w - bf2f(hi));
    int s = k >> 5, q = (k >> 3) & 3, j = k & 7;
    int idx = (((s * 128 + n) * 4 + q) * 8) + j;
    Whi[idx] = hi;
    Wlo[idx] = lo;
}

// ---------------- fused preamble: wcast(W1/W2), cntbs, LDS bucket-hist, zero(sums) ----------
__global__ __launch_bounds__(256) void k_pre(const float* __restrict__ W1, const float* __restrict__ W2,
                                             unsigned short* __restrict__ w1h, unsigned short* __restrict__ w1l,
                                             unsigned short* __restrict__ w2h, unsigned short* __restrict__ w2l,
                                             const int* __restrict__ dst, int* __restrict__ cnts,
                                             const int* __restrict__ batch, float* __restrict__ cnt,
                                             float* __restrict__ sums) {
    __shared__ int h[NBUCK];
    int b = blockIdx.x, t = threadIdx.x;
    if (b < WC_BLKS) {
        wcast_one(W1, w1h, w1l, b * 256 + t);
    } else if (b < 2 * WC_BLKS) {
        wcast_one(W2, w2h, w2l, (b - WC_BLKS) * 256 + t);
    } else if (b == 2 * WC_BLKS) {
        int g = t;
        int lo0 = 0, hi0 = N;
        while (lo0 < hi0) { int m = (lo0 + hi0) >> 1; if (batch[m] < g) lo0 = m + 1; else hi0 = m; }
        int lo1 = lo0, hi1 = N;
        while (lo1 < hi1) { int m = (lo1 + hi1) >> 1; if (batch[m] < g + 1) lo1 = m + 1; else hi1 = m; }
        cnt[g] = (float)(lo1 - lo0);
    } else if (b < PRE_SUM0) {
        int chunk = b - PRE_H0;
        for (int i = t; i < NBUCK; i += 256) h[i] = 0;
        __syncthreads();
        int base = chunk * CHUNK;
        for (int i = t; i < CHUNK; i += 256) {
            int e = base + i;
            if (e < E) atomicAdd(&h[dst[e] >> BSH], 1);   // LDS atomic
        }
        __syncthreads();
        for (int i = t; i < NBUCK; i += 256) cnts[chunk * NBUCK + i] = h[i];
    } else {
        int i = (b - PRE_SUM0) * 256 + t;
        if (i < G * F) sums[i] = 0.f;
    }
}

// ---------------- per-bucket scan over chunks: cnts -> within-bucket offsets + totals --------
__global__ __launch_bounds__(256) void k_colscan(int* __restrict__ cnts, int* __restrict__ btot) {
    int j = blockIdx.x * 256 + threadIdx.x;
    if (j >= NBUCK) return;
    int run = 0;
    for (int k = 0; k < NCHUNK; ++k) {
        int v = cnts[k * NBUCK + j];
        cnts[k * NBUCK + j] = run;
        run += v;
    }
    btot[j] = run;
}

// ---------------- scan bucket totals -> bucketbase (exclusive) ----------------
__global__ __launch_bounds__(256) void k_bucketscan(const int* __restrict__ btot,
                                                    int* __restrict__ bucketbase) {
    __shared__ int part[256];
    int t = threadIdx.x;
    constexpr int CH = (NBUCK + 255) / 256;   // 7
    int beg = t * CH;
    int end = (beg + CH < NBUCK) ? beg + CH : NBUCK;
    int tot[CH];
    int s = 0;
    for (int i = beg; i < end; ++i) {
        tot[i - beg] = btot[i];
        s += btot[i];
    }
    part[t] = s;
    __syncthreads();
    for (int off = 1; off < 256; off <<= 1) {
        int u = (t >= off) ? part[t - off] : 0;
        __syncthreads();
        part[t] += u;
        __syncthreads();
    }
    int run = (t == 0) ? 0 : part[t - 1];
    for (int i = beg; i < end; ++i) {
        bucketbase[i] = run;
        run += tot[i - beg];
    }
    if (t == 255) bucketbase[NBUCK] = part[255];  // == E
}

// ---------------- deterministic partition: edges -> bucket-contiguous staging (4B packed) ----
__global__ __launch_bounds__(256) void k_fillb(const int* __restrict__ src,
                                               const int* __restrict__ dst,
                                               const int* __restrict__ cnts,
                                               const int* __restrict__ bucketbase,
                                               unsigned int* __restrict__ staging) {
    __shared__ int lofs[NBUCK];
    int chunk = blockIdx.x, t = threadIdx.x;
    for (int i = t; i < NBUCK; i += 256)
        lofs[i] = bucketbase[i] + cnts[chunk * NBUCK + i];
    __syncthreads();
    int base = chunk * CHUNK;
    for (int i = t; i < CHUNK; i += 256) {
        int e = base + i;
        if (e < E) {
            int d = dst[e];
            int pos = atomicAdd(&lofs[d >> BSH], 1);      // LDS atomic
            staging[pos] = (unsigned int)src[e] | ((unsigned int)(d & (BNODES - 1)) << 16);
        }
    }
}

// ---------------- pass B: per-bucket counting sort by (dstLow5, srcSlice) ------------------
__global__ __launch_bounds__(256) void k_passB(const unsigned int* __restrict__ staging,
                                               const int* __restrict__ bucketbase,
                                               int* __restrict__ csr,
                                               int* __restrict__ rowstart,
                                               float* __restrict__ dinv) {
    __shared__ unsigned int ent[1024];        // mean 512, 11-sigma safe
    __shared__ int h[BNODES * 8], off_a[BNODES * 8];   // (node, slice) bins
    __shared__ int nodebase[BNODES], ndeg[BNODES];
    int b = blockIdx.x, t = threadIdx.x;
    int jb = bucketbase[b], je = bucketbase[b + 1];
    int M = je - jb;
    if (M > 1024) M = 1024;
    if (t < BNODES * 8) h[t] = 0;
    __syncthreads();

    for (int i = t; i < M; i += 256) {
        unsigned int en = staging[jb + i];
        ent[i] = en;
        int key = (((en >> 16) & (BNODES - 1)) << 3) | ((en & 0xFFFFu) >> SSH);
        atomicAdd(&h[key], 1);
    }
    __syncthreads();

    if (t < BNODES) {
        int s = 0;
#pragma unroll
        for (int c = 0; c < 8; ++c) s += h[t * 8 + c];
        ndeg[t] = s;
    }
    __syncthreads();
    if (t == 0) {
        int run = jb;
        for (int k = 0; k < BNODES; ++k) {
            nodebase[k] = run;
            run += ndeg[k];
        }
    }
    __syncthreads();
    if (t < BNODES) {
        int run = nodebase[t];
#pragma unroll
        for (int c = 0; c < 8; ++c) {
            off_a[t * 8 + c] = run;
            run += h[t * 8 + c];
        }
        int node = b * BNODES + t;
        if (node < N) {
            rowstart[node] = nodebase[t];
            dinv[node] = rsqrtf((float)(ndeg[t] + 1));   // +1 self-loop
        }
    }
    if (b == 0 && t == 0) rowstart[N] = E;
    __syncthreads();

    for (int i = t; i < M; i += 256) {
        unsigned int en = ent[i];
        int key = (((en >> 16) & (BNODES - 1)) << 3) | ((en & 0xFFFFu) >> SSH);
        int loc = atomicAdd(&off_a[key], 1);
        csr[loc] = (int)(en & 0xFFFFu);
    }
}

// ---------------- MFMA GEMM body (64-row tile): C16 = dinv[row] * (A @ W) ----------------
template <bool ABF16>
__device__ __forceinline__ void gemm_body(const void* __restrict__ Ain,
                                          const unsigned short* __restrict__ Wph,
                                          const unsigned short* __restrict__ Wpl,
                                          const float* __restrict__ dinv,
                                          unsigned short* __restrict__ C16,
                                          int row0, int tid) {
    __shared__ __align__(16) unsigned short Albs[64 * 136];  // row-major, pad 136

    if (ABF16) {
        const uint4* A8 = (const uint4*)Ain;
        for (int f = tid; f < 64 * 16; f += 256) {
            int r = f >> 4, kq = f & 15;
            int row = row0 + r;
            uint4 v = make_uint4(0u, 0u, 0u, 0u);
            if (row < N) v = A8[row * 16 + kq];
            *(uint4*)&Albs[r * 136 + kq * 8] = v;
        }
    } else {
        const float4* A4 = (const float4*)Ain;
        for (int f = tid; f < 64 * 32; f += 256) {
            int r = f >> 5, kq = f & 31;
            int row = row0 + r;
            float4 v = make_float4(0.f, 0.f, 0.f, 0.f);
            if (row < N) v = A4[row * 32 + kq];
            ushort4 o;
            o.x = f2bf(v.x); o.y = f2bf(v.y); o.z = f2bf(v.z); o.w = f2bf(v.w);
            *(ushort4*)&Albs[r * 136 + kq * 4] = o;
        }
    }
    __syncthreads();

    int wv = tid >> 6;
    int lane = tid & 63;
    int c16 = lane & 15;
    int q = lane >> 4;
    int m = wv * 16 + c16;

    floatx4 acc[8];
#pragma unroll
    for (int nt = 0; nt < 8; ++nt) acc[nt] = (floatx4){0.f, 0.f, 0.f, 0.f};

    const short8* WH = (const short8*)Wph;
    const short8* WL = (const short8*)Wpl;
#pragma unroll
    for (int s = 0; s < 4; ++s) {
        short8 a = *(const short8*)&Albs[m * 136 + s * 32 + q * 8];
        int wb = s * 512 + c16 * 4 + q;
#pragma unroll
        for (int nt = 0; nt < 8; ++nt) {
            acc[nt] = __builtin_amdgcn_mfma_f32_16x16x32_bf16(a, WH[wb + nt * 64], acc[nt], 0, 0, 0);
            acc[nt] = __builtin_amdgcn_mfma_f32_16x16x32_bf16(a, WL[wb + nt * 64], acc[nt], 0, 0, 0);
        }
    }

    int rbase = row0 + wv * 16 + q * 4;
#pragma unroll
    for (int r = 0; r < 4; ++r) {
        int row = rbase + r;
        if (row < N) {
            float dv = dinv[row];
#pragma unroll
            for (int nt = 0; nt < 8; ++nt)
                C16[row * 128 + nt * 16 + c16] = f2bf(acc[nt][r] * dv);
        }
    }
}

template <bool ABF16>
__global__ __launch_bounds__(256) void k_gemm(const void* __restrict__ Ain,
                                              const unsigned short* __restrict__ Wph,
                                              const unsigned short* __restrict__ Wpl,
                                              const float* __restrict__ dinv,
                                              unsigned short* __restrict__ C16) {
    gemm_body<ABF16>(Ain, Wph, Wpl, dinv, C16, blockIdx.x * 64, threadIdx.x);
}

// 8 bf16 (uint4) fma into 8 fp32 accumulators
__device__ inline void fma8(const uint4& u, float c, float* acc) {
    union { unsigned int i; float f; } a;
    a.i = u.x << 16;          acc[0] = fmaf(a.f, c, acc[0]);
    a.i = u.x & 0xFFFF0000u;  acc[1] = fmaf(a.f, c, acc[1]);
    a.i = u.y << 16;          acc[2] = fmaf(a.f, c, acc[2]);
    a.i = u.y & 0xFFFF0000u;  acc[3] = fmaf(a.f, c, acc[3]);
    a.i = u.z << 16;          acc[4] = fmaf(a.f, c, acc[4]);
    a.i = u.z & 0xFFFF0000u;  acc[5] = fmaf(a.f, c, acc[5]);
    a.i = u.w << 16;          acc[6] = fmaf(a.f, c, acc[6]);
    a.i = u.w & 0xFFFF0000u;  acc[7] = fmaf(a.f, c, acc[7]);
}

// agg inner loop: acc += Sum_{j in [jb,je)} tmp[csr[j]] (8-deep in flight)
__device__ __forceinline__ void agg_loop(const uint4* __restrict__ t8,
                                         const int* __restrict__ csr,
                                         int jb, int je, int lane, float* acc) {
    for (int j = jb; j < je; j += 8) {
        int e[8];
        float msk[8];
#pragma unroll
        for (int k = 0; k < 8; ++k) {
            int idx = j + k;
            e[k] = csr[idx < je ? idx : je - 1];
            msk[k] = (idx < je) ? 1.0f : 0.0f;
        }
        uint4 u[8];
#pragma unroll
        for (int k = 0; k < 8; ++k) u[k] = t8[e[k] * 16 + lane];
#pragma unroll
        for (int k = 0; k < 8; ++k) fma8(u[k], msk[k], acc);
    }
}

// ---------------- fused layer-1 agg + layer-2 GEMM (16 nodes/block) ----------------
__global__ __launch_bounds__(256) void k_agg1gemm(const unsigned short* __restrict__ tmp16,
                                                  const int* __restrict__ csr,
                                                  const int* __restrict__ rowstart,
                                                  const float* __restrict__ dinv,
                                                  const float* __restrict__ bias,
                                                  const unsigned short* __restrict__ w2h,
                                                  const unsigned short* __restrict__ w2l,
                                                  unsigned short* __restrict__ tmp2) {
    __shared__ __align__(16) unsigned short Albs[16 * 136];
    int tid = threadIdx.x;
    int row0 = blockIdx.x * 16;

    // ---- phase A: aggregation ----
    {
        int node = row0 + (tid >> 4);
        int lane = tid & 15;
        const uint4* t8 = (const uint4*)tmp16;
        float acc[8] = {0.f, 0.f, 0.f, 0.f, 0.f, 0.f, 0.f, 0.f};
        fma8(t8[node * 16 + lane], 1.0f, acc);
        agg_loop(t8, csr, rowstart[node], rowstart[node + 1], lane, acc);

        float di = dinv[node];
        const float4* b4 = (const float4*)bias;
        float4 ba = b4[lane * 2], bb = b4[lane * 2 + 1];
        uint4 o;
        o.x = pack2bf(fmaxf(fmaf(acc[0], di, ba.x), 0.f), fmaxf(fmaf(acc[1], di, ba.y), 0.f));
        o.y = pack2bf(fmaxf(fmaf(acc[2], di, ba.z), 0.f), fmaxf(fmaf(acc[3], di, ba.w), 0.f));
        o.z = pack2bf(fmaxf(fmaf(acc[4], di, bb.x), 0.f), fmaxf(fmaf(acc[5], di, bb.y), 0.f));
        o.w = pack2bf(fmaxf(fmaf(acc[6], di, bb.z), 0.f), fmaxf(fmaf(acc[7], di, bb.w), 0.f));
        *(uint4*)&Albs[(tid >> 4) * 136 + lane * 8] = o;
    }
    __syncthreads();

    // ---- phase B: 16-row MFMA gemm, 4 waves x 2 n-tiles ----
    int wv = tid >> 6;
    int lane = tid & 63;
    int c16 = lane & 15;
    int q = lane >> 4;

    floatx4 acc[2];
    acc[0] = (floatx4){0.f, 0.f, 0.f, 0.f};
    acc[1] = (floatx4){0.f, 0.f, 0.f, 0.f};

    const short8* WH = (const short8*)w2h;
    const short8* WL = (const short8*)w2l;
#pragma unroll
    for (int s = 0; s < 4; ++s) {
        short8 a = *(const short8*)&Albs[c16 * 136 + s * 32 + q * 8];
        int wb = s * 512 + c16 * 4 + q;
#pragma unroll
        for (int i = 0; i < 2; ++i) {
            int nt = wv * 2 + i;
            acc[i] = __builtin_amdgcn_mfma_f32_16x16x32_bf16(a, WH[wb + nt * 64], acc[i], 0, 0, 0);
            acc[i] = __builtin_amdgcn_mfma_f32_16x16x32_bf16(a, WL[wb + nt * 64], acc[i], 0, 0, 0);
        }
    }

    int rbase = row0 + q * 4;
#pragma unroll
    for (int r = 0; r < 4; ++r) {
        int row = rbase + r;
        float dv = dinv[row];
#pragma unroll
        for (int i = 0; i < 2; ++i) {
            int nt = wv * 2 + i;
            tmp2[row * 128 + nt * 16 + c16] = f2bf(acc[i][r] * dv);
        }
    }
}

// ---------------- layer-2 aggregation (standalone) ----------------
__global__ __launch_bounds__(256) void k_agg(const unsigned short* __restrict__ tmp16,
                                             const int* __restrict__ csr,
                                             const int* __restrict__ rowstart,
                                             const float* __restrict__ dinv,
                                             const float* __restrict__ bias,
                                             unsigned short* __restrict__ out16) {
    int node = (blockIdx.x * blockDim.x + threadIdx.x) >> 4;
    int lane = threadIdx.x & 15;
    if (node >= N) return;
    const uint4* t8 = (const uint4*)tmp16;
    float acc[8] = {0.f, 0.f, 0.f, 0.f, 0.f, 0.f, 0.f, 0.f};
    fma8(t8[node * 16 + lane], 1.0f, acc);
    agg_loop(t8, csr, rowstart[node], rowstart[node + 1], lane, acc);

    float di = dinv[node];
    const float4* b4 = (const float4*)bias;
    float4 ba = b4[lane * 2], bb = b4[lane * 2 + 1];
    uint4 o;
    o.x = pack2bf(fmaxf(fmaf(acc[0], di, ba.x), 0.f), fmaxf(fmaf(acc[1], di, ba.y), 0.f));
    o.y = pack2bf(fmaxf(fmaf(acc[2], di, ba.z), 0.f), fmaxf(fmaf(acc[3], di, ba.w), 0.f));
    o.z = pack2bf(fmaxf(fmaf(acc[4], di, bb.x), 0.f), fmaxf(fmaf(acc[5], di, bb.y), 0.f));
    o.w = pack2bf(fmaxf(fmaf(acc[6], di, bb.z), 0.f), fmaxf(fmaf(acc[7], di, bb.w), 0.f));
    ((uint4*)out16)[node * 16 + lane] = o;
}

// ---------------- mean-pool accumulate over bf16 h (batch is sorted; 256-node runs) --------
__global__ void k_pool(const unsigned short* __restrict__ h16, const int* __restrict__ batch,
                       float* __restrict__ sums) {
    int grp = (blockIdx.x * blockDim.x + threadIdx.x) >> 4;
    int lane = threadIdx.x & 15;
    int base = grp * POOL_RUN;
    if (base >= N) return;
    int end = (base + POOL_RUN < N) ? base + POOL_RUN : N;
    float acc[8] = {0.f, 0.f, 0.f, 0.f, 0.f, 0.f, 0.f, 0.f};
    const uint4* h4 = (const uint4*)h16;
    int curb = batch[base];
    for (int i = base; i < end; ++i) {
        int b = batch[i];
        if (b != curb) {
            float* sp = &sums[curb * F + lane * 8];
#pragma unroll
            for (int k = 0; k < 8; ++k) { atomicAdd(sp + k, acc[k]); acc[k] = 0.f; }
            curb = b;
        }
        fma8(h4[i * 16 + lane], 1.0f, acc);
    }
    float* sp = &sums[curb * F + lane * 8];
#pragma unroll
    for (int k = 0; k < 8; ++k) atomicAdd(sp + k, acc[k]);
}

// ---------------- fused fc + head ----------------
__global__ __launch_bounds__(128) void k_fchead(const float* __restrict__ sums,
                                                const float* __restrict__ cnt,
                                                const float* __restrict__ Wfc,
                                                const float* __restrict__ bfc,
                                                const float* __restrict__ Wh,
                                                const float* __restrict__ bh,
                                                float* __restrict__ out) {
    __shared__ float p[128];
    __shared__ float zs[128];
    int g = blockIdx.x, t = threadIdx.x;
    float inv = 1.0f / fmaxf(cnt[g], 1.0f);
    p[t] = sums[g * F + t] * inv;
    __syncthreads();
    float acc = bfc[t];
    for (int k = 0; k < F; ++k) acc = fmaf(p[k], Wfc[k * F + t], acc);
    zs[t] = fmaxf(acc, 0.f);
    __syncthreads();
    if (t < T * 2) {
        int task = t >> 1, c = t & 1;
        float a = bh[task * 2 + c];
        const float* wr = &Wh[task * F * 2 + c];
        for (int h = 0; h < F; ++h) a = fmaf(zs[h], wr[h * 2], a);
        out[task * (G * 2) + g * 2 + c] = a;
    }
}

extern "C" void kernel_launch(void* const* d_in, const int* in_sizes, int n_in,
                              void* d_out, int out_size, void* d_ws, size_t ws_size,
                              hipStream_t stream) {
    const float* x    = (const float*)d_in[0];
    const int*   ei   = (const int*)d_in[1];      // [2,E]: row0=src, row1=dst
    const int*   batch= (const int*)d_in[2];
    const float* W1   = (const float*)d_in[3];
    const float* b1   = (const float*)d_in[4];
    const float* W2   = (const float*)d_in[5];
    const float* b2   = (const float*)d_in[6];
    const float* Wfc  = (const float*)d_in[7];
    const float* bfc  = (const float*)d_in[8];
    const float* Wh   = (const float*)d_in[9];
    const float* bh   = (const float*)d_in[10];
    float* out = (float*)d_out;

    const int* srcp = ei;
    const int* dstp = ei + E;

    char* w = (char*)d_ws;
    auto alloc = [&](size_t bytes) {
        char* p = w;
        w += (bytes + 255) & ~(size_t)255;
        return p;
    };
    unsigned short* tmp16 = (unsigned short*)alloc((size_t)N * F * 2);
    unsigned short* tmp2  = (unsigned short*)alloc((size_t)N * F * 2);
    unsigned short* hbuf16= (unsigned short*)alloc((size_t)N * F * 2);
    int*   csr      = (int*)  alloc((size_t)E * 4);
    unsigned int* staging = (unsigned int*)alloc((size_t)E * 4);
    int*   cnts     = (int*)  alloc((size_t)NCHUNK * NBUCK * 4);
    int*   btot     = (int*)  alloc((size_t)NBUCK * 4);
    int*   bucketbase=(int*)  alloc((size_t)(NBUCK + 1) * 4);
    int*   rowstart = (int*)  alloc((size_t)(N + 1) * 4);
    float* dinv     = (float*)alloc((size_t)N * 4);
    float* sums     = (float*)alloc((size_t)G * F * 4);
    float* cnt      = (float*)alloc((size_t)G * 4);
    unsigned short* w1h = (unsigned short*)alloc((size_t)F * F * 2);
    unsigned short* w1l = (unsigned short*)alloc((size_t)F * F * 2);
    unsigned short* w2h = (unsigned short*)alloc((size_t)F * F * 2);
    unsigned short* w2l = (unsigned short*)alloc((size_t)F * F * 2);

    // fused preamble: wcast W1/W2, cntbs, per-chunk LDS bucket histogram, zero sums
    k_pre<<<PRE_BLKS, 256, 0, stream>>>(W1, W2, w1h, w1l, w2h, w2l,
                                        dstp, cnts, batch, cnt, sums);

    // deterministic radix partition (zero global atomics); csr sorted by src-slice per node
    k_colscan<<<(NBUCK + 255) / 256, 256, 0, stream>>>(cnts, btot);
    k_bucketscan<<<1, 256, 0, stream>>>(btot, bucketbase);
    k_fillb<<<NCHUNK, 256, 0, stream>>>(srcp, dstp, cnts, bucketbase, staging);
    k_passB<<<NBUCK, 256, 0, stream>>>(staging, bucketbase, csr, rowstart, dinv);

    // layer-1 GEMM (dinv-prescaled output)
    k_gemm<false><<<GB1, 256, 0, stream>>>(x, w1h, w1l, dinv, tmp16);

    // fused: layer-1 aggregation + layer-2 GEMM (h1 stays in LDS)
    k_agg1gemm<<<AGB, 256, 0, stream>>>(tmp16, csr, rowstart, dinv, b1, w2h, w2l, tmp2);

    // layer-2 aggregation
    k_agg<<<(N * 16 + 255) / 256, 256, 0, stream>>>(tmp2, csr, rowstart, dinv, b2, hbuf16);

    // pooling (256-node runs -> 4x fewer atomic flushes)
    k_pool<<<(NPGRP * 16 + 255) / 256, 256, 0, stream>>>(hbuf16, batch, sums);

    // fc + heads (fused)
    k_fchead<<<G, 128, 0, stream>>>(sums, cnt, Wfc, bfc, Wh, bh, out);
}

// Round 16
// 250.165 us; speedup vs baseline: 1.4082x; 1.4082x over previous
//
#include <hip/hip_runtime.h>
#include <math.h>

constexpr int N = 50000;   // nodes
constexpr int E = 800000;  // edges (without self-loops)
constexpr int F = 128;     // features / hidden
constexpr int G = 256;     // graphs
constexpr int T = 4;       // tasks

constexpr int BSH   = 5;                         // 32 nodes per bucket
constexpr int BNODES= 1 << BSH;
constexpr int NBUCK = (N + BNODES - 1) / BNODES; // 1563
constexpr int CHUNK = 2048;                      // edges per partition block (391 blocks)
constexpr int NCHUNK= (E + CHUNK - 1) / CHUNK;   // 391
constexpr int SSH   = 13;                        // src-slice shift: 8192-node slices

// k_pre block-range layout
constexpr int WC_BLKS  = (F * F + 255) / 256;    // 64
constexpr int PRE_H0   = 2 * WC_BLKS;            // 128 (hist chunks start)
constexpr int PRE_BLKS = PRE_H0 + NCHUNK;        // 519

constexpr int GB1 = (N + 63) / 64;               // 782 gemm blocks
constexpr int AGB = N / 16;                      // 3125 fused agg+gemm blocks

typedef __attribute__((ext_vector_type(8))) short short8;
typedef __attribute__((ext_vector_type(4))) float floatx4;

// bf16 <-> fp32 helpers (RNE on pack; values are finite)
__device__ inline float bf2f(unsigned short u) {
    union { unsigned int i; float f; } v;
    v.i = ((unsigned int)u) << 16;
    return v.f;
}
__device__ inline unsigned short f2bf(float f) {
    union { float f; unsigned int i; } v;
    v.f = f;
    unsigned int r = v.i + 0x7FFF + ((v.i >> 16) & 1);
    return (unsigned short)(r >> 16);
}
__device__ inline unsigned int pack2bf(float a, float b) {
    return (unsigned int)f2bf(a) | ((unsigned int)f2bf(b) << 16);
}

// pack W (fp32) -> MFMA-B-fragment order, hi/lo bf16 split
__device__ inline void wcast_one(const float* __restrict__ W,
                                 unsigned short* __restrict__ Whi,
                                 unsigned short* __restrict__ Wlo, int i) {
    if (i >= F * F) return;
    int k = i >> 7, n = i & 127;
    float w = W[i];
    unsigned short hi = f2bf(w);
    unsigned short lo = f2bf(w - bf2f(hi));
    int s = k >> 5, q = (k >> 3) & 3, j = k & 7;
    int idx = (((s * 128 + n) * 4 + q) * 8) + j;
    Whi[idx] = hi;
    Wlo[idx] = lo;
}

// ---------------- fused preamble: wcast(W1/W2) + per-chunk LDS bucket histogram ----------
__global__ __launch_bounds__(256) void k_pre(const float* __restrict__ W1, const float* __restrict__ W2,
                                             unsigned short* __restrict__ w1h, unsigned short* __restrict__ w1l,
                                             unsigned short* __restrict__ w2h, unsigned short* __restrict__ w2l,
                                             const int* __restrict__ dst, int* __restrict__ cnts) {
    __shared__ int h[NBUCK];
    int b = blockIdx.x, t = threadIdx.x;
    if (b < WC_BLKS) {
        wcast_one(W1, w1h, w1l, b * 256 + t);
    } else if (b < 2 * WC_BLKS) {
        wcast_one(W2, w2h, w2l, (b - WC_BLKS) * 256 + t);
    } else {
        int chunk = b - PRE_H0;
        for (int i = t; i < NBUCK; i += 256) h[i] = 0;
        __syncthreads();
        int base = chunk * CHUNK;
        for (int i = t; i < CHUNK; i += 256) {
            int e = base + i;
            if (e < E) atomicAdd(&h[dst[e] >> BSH], 1);   // LDS atomic
        }
        __syncthreads();
        for (int i = t; i < NBUCK; i += 256) cnts[chunk * NBUCK + i] = h[i];
    }
}

// ---------------- per-bucket scan over chunks: cnts -> within-bucket offsets + totals --------
__global__ __launch_bounds__(256) void k_colscan(int* __restrict__ cnts, int* __restrict__ btot) {
    int j = blockIdx.x * 256 + threadIdx.x;
    if (j >= NBUCK) return;
    int run = 0;
    for (int k = 0; k < NCHUNK; ++k) {
        int v = cnts[k * NBUCK + j];
        cnts[k * NBUCK + j] = run;
        run += v;
    }
    btot[j] = run;
}

// ---------------- scan bucket totals -> bucketbase (exclusive) ----------------
__global__ __launch_bounds__(256) void k_bucketscan(const int* __restrict__ btot,
                                                    int* __restrict__ bucketbase) {
    __shared__ int part[256];
    int t = threadIdx.x;
    constexpr int CH = (NBUCK + 255) / 256;   // 7
    int beg = t * CH;
    int end = (beg + CH < NBUCK) ? beg + CH : NBUCK;
    int tot[CH];
    int s = 0;
    for (int i = beg; i < end; ++i) {
        tot[i - beg] = btot[i];
        s += btot[i];
    }
    part[t] = s;
    __syncthreads();
    for (int off = 1; off < 256; off <<= 1) {
        int u = (t >= off) ? part[t - off] : 0;
        __syncthreads();
        part[t] += u;
        __syncthreads();
    }
    int run = (t == 0) ? 0 : part[t - 1];
    for (int i = beg; i < end; ++i) {
        bucketbase[i] = run;
        run += tot[i - beg];
    }
    if (t == 255) bucketbase[NBUCK] = part[255];  // == E
}

// ---------------- deterministic partition: edges -> bucket-contiguous staging (4B packed) ----
__global__ __launch_bounds__(256) void k_fillb(const int* __restrict__ src,
                                               const int* __restrict__ dst,
                                               const int* __restrict__ cnts,
                                               const int* __restrict__ bucketbase,
                                               unsigned int* __restrict__ staging) {
    __shared__ int lofs[NBUCK];
    int chunk = blockIdx.x, t = threadIdx.x;
    for (int i = t; i < NBUCK; i += 256)
        lofs[i] = bucketbase[i] + cnts[chunk * NBUCK + i];
    __syncthreads();
    int base = chunk * CHUNK;
    for (int i = t; i < CHUNK; i += 256) {
        int e = base + i;
        if (e < E) {
            int d = dst[e];
            int pos = atomicAdd(&lofs[d >> BSH], 1);      // LDS atomic
            staging[pos] = (unsigned int)src[e] | ((unsigned int)(d & (BNODES - 1)) << 16);
        }
    }
}

// ---------------- pass B: per-bucket counting sort by (dstLow5, srcSlice) ------------------
__global__ __launch_bounds__(256) void k_passB(const unsigned int* __restrict__ staging,
                                               const int* __restrict__ bucketbase,
                                               int* __restrict__ csr,
                                               int* __restrict__ rowstart,
                                               float* __restrict__ dinv) {
    __shared__ unsigned int ent[1024];        // mean 512, 11-sigma safe
    __shared__ int h[BNODES * 8], off_a[BNODES * 8];   // (node, slice) bins
    __shared__ int nodebase[BNODES], ndeg[BNODES];
    int b = blockIdx.x, t = threadIdx.x;
    int jb = bucketbase[b], je = bucketbase[b + 1];
    int M = je - jb;
    if (M > 1024) M = 1024;
    if (t < BNODES * 8) h[t] = 0;
    __syncthreads();

    for (int i = t; i < M; i += 256) {
        unsigned int en = staging[jb + i];
        ent[i] = en;
        int key = (((en >> 16) & (BNODES - 1)) << 3) | ((en & 0xFFFFu) >> SSH);
        atomicAdd(&h[key], 1);
    }
    __syncthreads();

    if (t < BNODES) {
        int s = 0;
#pragma unroll
        for (int c = 0; c < 8; ++c) s += h[t * 8 + c];
        ndeg[t] = s;
    }
    __syncthreads();
    if (t == 0) {
        int run = jb;
        for (int k = 0; k < BNODES; ++k) {
            nodebase[k] = run;
            run += ndeg[k];
        }
    }
    __syncthreads();
    if (t < BNODES) {
        int run = nodebase[t];
#pragma unroll
        for (int c = 0; c < 8; ++c) {
            off_a[t * 8 + c] = run;
            run += h[t * 8 + c];
        }
        int node = b * BNODES + t;
        if (node < N) {
            rowstart[node] = nodebase[t];
            dinv[node] = rsqrtf((float)(ndeg[t] + 1));   // +1 self-loop
        }
    }
    if (b == 0 && t == 0) rowstart[N] = E;
    __syncthreads();

    for (int i = t; i < M; i += 256) {
        unsigned int en = ent[i];
        int key = (((en >> 16) & (BNODES - 1)) << 3) | ((en & 0xFFFFu) >> SSH);
        int loc = atomicAdd(&off_a[key], 1);
        csr[loc] = (int)(en & 0xFFFFu);
    }
}

// ---------------- MFMA GEMM body (64-row tile): C16 = dinv[row] * (A @ W) ----------------
template <bool ABF16>
__device__ __forceinline__ void gemm_body(const void* __restrict__ Ain,
                                          const unsigned short* __restrict__ Wph,
                                          const unsigned short* __restrict__ Wpl,
                                          const float* __restrict__ dinv,
                                          unsigned short* __restrict__ C16,
                                          int row0, int tid) {
    __shared__ __align__(16) unsigned short Albs[64 * 136];  // row-major, pad 136

    if (ABF16) {
        const uint4* A8 = (const uint4*)Ain;
        for (int f = tid; f < 64 * 16; f += 256) {
            int r = f >> 4, kq = f & 15;
            int row = row0 + r;
            uint4 v = make_uint4(0u, 0u, 0u, 0u);
            if (row < N) v = A8[row * 16 + kq];
            *(uint4*)&Albs[r * 136 + kq * 8] = v;
        }
    } else {
        const float4* A4 = (const float4*)Ain;
        for (int f = tid; f < 64 * 32; f += 256) {
            int r = f >> 5, kq = f & 31;
            int row = row0 + r;
            float4 v = make_float4(0.f, 0.f, 0.f, 0.f);
            if (row < N) v = A4[row * 32 + kq];
            ushort4 o;
            o.x = f2bf(v.x); o.y = f2bf(v.y); o.z = f2bf(v.z); o.w = f2bf(v.w);
            *(ushort4*)&Albs[r * 136 + kq * 4] = o;
        }
    }
    __syncthreads();

    int wv = tid >> 6;
    int lane = tid & 63;
    int c16 = lane & 15;
    int q = lane >> 4;
    int m = wv * 16 + c16;

    floatx4 acc[8];
#pragma unroll
    for (int nt = 0; nt < 8; ++nt) acc[nt] = (floatx4){0.f, 0.f, 0.f, 0.f};

    const short8* WH = (const short8*)Wph;
    const short8* WL = (const short8*)Wpl;
#pragma unroll
    for (int s = 0; s < 4; ++s) {
        short8 a = *(const short8*)&Albs[m * 136 + s * 32 + q * 8];
        int wb = s * 512 + c16 * 4 + q;
#pragma unroll
        for (int nt = 0; nt < 8; ++nt) {
            acc[nt] = __builtin_amdgcn_mfma_f32_16x16x32_bf16(a, WH[wb + nt * 64], acc[nt], 0, 0, 0);
            acc[nt] = __builtin_amdgcn_mfma_f32_16x16x32_bf16(a, WL[wb + nt * 64], acc[nt], 0, 0, 0);
        }
    }

    int rbase = row0 + wv * 16 + q * 4;
#pragma unroll
    for (int r = 0; r < 4; ++r) {
        int row = rbase + r;
        if (row < N) {
            float dv = dinv[row];
#pragma unroll
            for (int nt = 0; nt < 8; ++nt)
                C16[row * 128 + nt * 16 + c16] = f2bf(acc[nt][r] * dv);
        }
    }
}

template <bool ABF16>
__global__ __launch_bounds__(256) void k_gemm(const void* __restrict__ Ain,
                                              const unsigned short* __restrict__ Wph,
                                              const unsigned short* __restrict__ Wpl,
                                              const float* __restrict__ dinv,
                                              unsigned short* __restrict__ C16) {
    gemm_body<ABF16>(Ain, Wph, Wpl, dinv, C16, blockIdx.x * 64, threadIdx.x);
}

// 8 bf16 (uint4) fma into 8 fp32 accumulators
__device__ inline void fma8(const uint4& u, float c, float* acc) {
    union { unsigned int i; float f; } a;
    a.i = u.x << 16;          acc[0] = fmaf(a.f, c, acc[0]);
    a.i = u.x & 0xFFFF0000u;  acc[1] = fmaf(a.f, c, acc[1]);
    a.i = u.y << 16;          acc[2] = fmaf(a.f, c, acc[2]);
    a.i = u.y & 0xFFFF0000u;  acc[3] = fmaf(a.f, c, acc[3]);
    a.i = u.z << 16;          acc[4] = fmaf(a.f, c, acc[4]);
    a.i = u.z & 0xFFFF0000u;  acc[5] = fmaf(a.f, c, acc[5]);
    a.i = u.w << 16;          acc[6] = fmaf(a.f, c, acc[6]);
    a.i = u.w & 0xFFFF0000u;  acc[7] = fmaf(a.f, c, acc[7]);
}

// agg inner loop: acc += Sum_{j in [jb,je)} tmp[csr[j]] (8-deep in flight)
__device__ __forceinline__ void agg_loop(const uint4* __restrict__ t8,
                                         const int* __restrict__ csr,
                                         int jb, int je, int lane, float* acc) {
    for (int j = jb; j < je; j += 8) {
        int e[8];
        float msk[8];
#pragma unroll
        for (int k = 0; k < 8; ++k) {
            int idx = j + k;
            e[k] = csr[idx < je ? idx : je - 1];
            msk[k] = (idx < je) ? 1.0f : 0.0f;
        }
        uint4 u[8];
#pragma unroll
        for (int k = 0; k < 8; ++k) u[k] = t8[e[k] * 16 + lane];
#pragma unroll
        for (int k = 0; k < 8; ++k) fma8(u[k], msk[k], acc);
    }
}

// ---------------- fused layer-1 agg + layer-2 GEMM (16 nodes/block) ----------------
__global__ __launch_bounds__(256) void k_agg1gemm(const unsigned short* __restrict__ tmp16,
                                                  const int* __restrict__ csr,
                                                  const int* __restrict__ rowstart,
                                                  const float* __restrict__ dinv,
                                                  const float* __restrict__ bias,
                                                  const unsigned short* __restrict__ w2h,
                                                  const unsigned short* __restrict__ w2l,
                                                  unsigned short* __restrict__ tmp2) {
    __shared__ __align__(16) unsigned short Albs[16 * 136];
    int tid = threadIdx.x;
    int row0 = blockIdx.x * 16;

    // ---- phase A: aggregation ----
    {
        int node = row0 + (tid >> 4);
        int lane = tid & 15;
        const uint4* t8 = (const uint4*)tmp16;
        float acc[8] = {0.f, 0.f, 0.f, 0.f, 0.f, 0.f, 0.f, 0.f};
        fma8(t8[node * 16 + lane], 1.0f, acc);
        agg_loop(t8, csr, rowstart[node], rowstart[node + 1], lane, acc);

        float di = dinv[node];
        const float4* b4 = (const float4*)bias;
        float4 ba = b4[lane * 2], bb = b4[lane * 2 + 1];
        uint4 o;
        o.x = pack2bf(fmaxf(fmaf(acc[0], di, ba.x), 0.f), fmaxf(fmaf(acc[1], di, ba.y), 0.f));
        o.y = pack2bf(fmaxf(fmaf(acc[2], di, ba.z), 0.f), fmaxf(fmaf(acc[3], di, ba.w), 0.f));
        o.z = pack2bf(fmaxf(fmaf(acc[4], di, bb.x), 0.f), fmaxf(fmaf(acc[5], di, bb.y), 0.f));
        o.w = pack2bf(fmaxf(fmaf(acc[6], di, bb.z), 0.f), fmaxf(fmaf(acc[7], di, bb.w), 0.f));
        *(uint4*)&Albs[(tid >> 4) * 136 + lane * 8] = o;
    }
    __syncthreads();

    // ---- phase B: 16-row MFMA gemm, 4 waves x 2 n-tiles ----
    int wv = tid >> 6;
    int lane = tid & 63;
    int c16 = lane & 15;
    int q = lane >> 4;

    floatx4 acc[2];
    acc[0] = (floatx4){0.f, 0.f, 0.f, 0.f};
    acc[1] = (floatx4){0.f, 0.f, 0.f, 0.f};

    const short8* WH = (const short8*)w2h;
    const short8* WL = (const short8*)w2l;
#pragma unroll
    for (int s = 0; s < 4; ++s) {
        short8 a = *(const short8*)&Albs[c16 * 136 + s * 32 + q * 8];
        int wb = s * 512 + c16 * 4 + q;
#pragma unroll
        for (int i = 0; i < 2; ++i) {
            int nt = wv * 2 + i;
            acc[i] = __builtin_amdgcn_mfma_f32_16x16x32_bf16(a, WH[wb + nt * 64], acc[i], 0, 0, 0);
            acc[i] = __builtin_amdgcn_mfma_f32_16x16x32_bf16(a, WL[wb + nt * 64], acc[i], 0, 0, 0);
        }
    }

    int rbase = row0 + q * 4;
#pragma unroll
    for (int r = 0; r < 4; ++r) {
        int row = rbase + r;
        float dv = dinv[row];
#pragma unroll
        for (int i = 0; i < 2; ++i) {
            int nt = wv * 2 + i;
            tmp2[row * 128 + nt * 16 + c16] = f2bf(acc[i][r] * dv);
        }
    }
}

// ---------------- layer-2 aggregation (standalone) ----------------
__global__ __launch_bounds__(256) void k_agg(const unsigned short* __restrict__ tmp16,
                                             const int* __restrict__ csr,
                                             const int* __restrict__ rowstart,
                                             const float* __restrict__ dinv,
                                             const float* __restrict__ bias,
                                             unsigned short* __restrict__ out16) {
    int node = (blockIdx.x * blockDim.x + threadIdx.x) >> 4;
    int lane = threadIdx.x & 15;
    if (node >= N) return;
    const uint4* t8 = (const uint4*)tmp16;
    float acc[8] = {0.f, 0.f, 0.f, 0.f, 0.f, 0.f, 0.f, 0.f};
    fma8(t8[node * 16 + lane], 1.0f, acc);
    agg_loop(t8, csr, rowstart[node], rowstart[node + 1], lane, acc);

    float di = dinv[node];
    const float4* b4 = (const float4*)bias;
    float4 ba = b4[lane * 2], bb = b4[lane * 2 + 1];
    uint4 o;
    o.x = pack2bf(fmaxf(fmaf(acc[0], di, ba.x), 0.f), fmaxf(fmaf(acc[1], di, ba.y), 0.f));
    o.y = pack2bf(fmaxf(fmaf(acc[2], di, ba.z), 0.f), fmaxf(fmaf(acc[3], di, ba.w), 0.f));
    o.z = pack2bf(fmaxf(fmaf(acc[4], di, bb.x), 0.f), fmaxf(fmaf(acc[5], di, bb.y), 0.f));
    o.w = pack2bf(fmaxf(fmaf(acc[6], di, bb.z), 0.f), fmaxf(fmaf(acc[7], di, bb.w), 0.f));
    ((uint4*)out16)[node * 16 + lane] = o;
}

// ---------------- pooling: one block per graph, LDS tree-reduce, zero atomics ---------------
__global__ __launch_bounds__(256) void k_poolg(const unsigned short* __restrict__ h16,
                                               const int* __restrict__ batch,
                                               float* __restrict__ pooled) {
    __shared__ float red[16][128];            // 8 KB
    int g = blockIdx.x, t = threadIdx.x;
    int rg = t >> 4, lane = t & 15;

    int lo = 0, hi = N;                       // lower_bound(g)
    while (lo < hi) { int m = (lo + hi) >> 1; if (batch[m] < g) lo = m + 1; else hi = m; }
    int lo1 = lo, hi1 = N;                    // lower_bound(g+1)
    while (lo1 < hi1) { int m = (lo1 + hi1) >> 1; if (batch[m] < g + 1) lo1 = m + 1; else hi1 = m; }
    int cnt = lo1 - lo;

    float acc[8] = {0.f, 0.f, 0.f, 0.f, 0.f, 0.f, 0.f, 0.f};
    const uint4* h4 = (const uint4*)h16;
    for (int i = lo + rg; i < lo1; i += 16)
        fma8(h4[i * 16 + lane], 1.0f, acc);
#pragma unroll
    for (int k = 0; k < 8; ++k) red[rg][lane * 8 + k] = acc[k];
    __syncthreads();

    if (t < 128) {
        float s = 0.f;
#pragma unroll
        for (int r = 0; r < 16; ++r) s += red[r][t];
        pooled[g * F + t] = s / (float)((cnt > 1) ? cnt : 1);
    }
}

// ---------------- fused fc + head (reads pooled directly) ----------------
__global__ __launch_bounds__(128) void k_fchead(const float* __restrict__ pooled,
                                                const float* __restrict__ Wfc,
                                                const float* __restrict__ bfc,
                                                const float* __restrict__ Wh,
                                                const float* __restrict__ bh,
                                                float* __restrict__ out) {
    __shared__ float p[128];
    __shared__ float zs[128];
    int g = blockIdx.x, t = threadIdx.x;
    p[t] = pooled[g * F + t];
    __syncthreads();
    float acc = bfc[t];
    for (int k = 0; k < F; ++k) acc = fmaf(p[k], Wfc[k * F + t], acc);
    zs[t] = fmaxf(acc, 0.f);
    __syncthreads();
    if (t < T * 2) {
        int task = t >> 1, c = t & 1;
        float a = bh[task * 2 + c];
        const float* wr = &Wh[task * F * 2 + c];
        for (int h = 0; h < F; ++h) a = fmaf(zs[h], wr[h * 2], a);
        out[task * (G * 2) + g * 2 + c] = a;
    }
}

extern "C" void kernel_launch(void* const* d_in, const int* in_sizes, int n_in,
                              void* d_out, int out_size, void* d_ws, size_t ws_size,
                              hipStream_t stream) {
    const float* x    = (const float*)d_in[0];
    const int*   ei   = (const int*)d_in[1];      // [2,E]: row0=src, row1=dst
    const int*   batch= (const int*)d_in[2];
    const float* W1   = (const float*)d_in[3];
    const float* b1   = (const float*)d_in[4];
    const float* W2   = (const float*)d_in[5];
    const float* b2   = (const float*)d_in[6];
    const float* Wfc  = (const float*)d_in[7];
    const float* bfc  = (const float*)d_in[8];
    const float* Wh   = (const float*)d_in[9];
    const float* bh   = (const float*)d_in[10];
    float* out = (float*)d_out;

    const int* srcp = ei;
    const int* dstp = ei + E;

    char* w = (char*)d_ws;
    auto alloc = [&](size_t bytes) {
        char* p = w;
        w += (bytes + 255) & ~(size_t)255;
        return p;
    };
    unsigned short* tmp16 = (unsigned short*)alloc((size_t)N * F * 2);
    unsigned short* tmp2  = (unsigned short*)alloc((size_t)N * F * 2);
    unsigned short* hbuf16= (unsigned short*)alloc((size_t)N * F * 2);
    int*   csr      = (int*)  alloc((size_t)E * 4);
    unsigned int* staging = (unsigned int*)alloc((size_t)E * 4);
    int*   cnts     = (int*)  alloc((size_t)NCHUNK * NBUCK * 4);
    int*   btot     = (int*)  alloc((size_t)NBUCK * 4);
    int*   bucketbase=(int*)  alloc((size_t)(NBUCK + 1) * 4);
    int*   rowstart = (int*)  alloc((size_t)(N + 1) * 4);
    float* dinv     = (float*)alloc((size_t)N * 4);
    float* pooled   = (float*)alloc((size_t)G * F * 4);
    unsigned short* w1h = (unsigned short*)alloc((size_t)F * F * 2);
    unsigned short* w1l = (unsigned short*)alloc((size_t)F * F * 2);
    unsigned short* w2h = (unsigned short*)alloc((size_t)F * F * 2);
    unsigned short* w2l = (unsigned short*)alloc((size_t)F * F * 2);

    // fused preamble: wcast W1/W2 + per-chunk LDS bucket histogram
    k_pre<<<PRE_BLKS, 256, 0, stream>>>(W1, W2, w1h, w1l, w2h, w2l, dstp, cnts);

    // deterministic radix partition (zero global atomics); csr sorted by src-slice per node
    k_colscan<<<(NBUCK + 255) / 256, 256, 0, stream>>>(cnts, btot);
    k_bucketscan<<<1, 256, 0, stream>>>(btot, bucketbase);
    k_fillb<<<NCHUNK, 256, 0, stream>>>(srcp, dstp, cnts, bucketbase, staging);
    k_passB<<<NBUCK, 256, 0, stream>>>(staging, bucketbase, csr, rowstart, dinv);

    // layer-1 GEMM (dinv-prescaled output)
    k_gemm<false><<<GB1, 256, 0, stream>>>(x, w1h, w1l, dinv, tmp16);

    // fused: layer-1 aggregation + layer-2 GEMM (h1 stays in LDS)
    k_agg1gemm<<<AGB, 256, 0, stream>>>(tmp16, csr, rowstart, dinv, b1, w2h, w2l, tmp2);

    // layer-2 aggregation
    k_agg<<<(N * 16 + 255) / 256, 256, 0, stream>>>(tmp2, csr, rowstart, dinv, b2, hbuf16);

    // pooling: one block per graph, no atomics
    k_poolg<<<G, 256, 0, stream>>>(hbuf16, batch, pooled);

    // fc + heads (fused)
    k_fchead<<<G, 128, 0, stream>>>(pooled, Wfc, bfc, Wh, bh, out);
}

// Round 17
// 244.973 us; speedup vs baseline: 1.4381x; 1.0212x over previous
//
#include <hip/hip_runtime.h>
#include <math.h>

constexpr int N = 50000;   // nodes
constexpr int E = 800000;  // edges (without self-loops)
constexpr int F = 128;     // features / hidden
constexpr int G = 256;     // graphs
constexpr int T = 4;       // tasks

constexpr int BSH   = 5;                         // 32 nodes per bucket
constexpr int BNODES= 1 << BSH;
constexpr int NBUCK = (N + BNODES - 1) / BNODES; // 1563
constexpr int CHUNK = 2048;                      // edges per partition block (391 blocks)
constexpr int NCHUNK= (E + CHUNK - 1) / CHUNK;   // 391
constexpr int SSH   = 13;                        // src-slice shift: 8192-node slices

// k_pre block-range layout
constexpr int WC_BLKS  = (F * F + 255) / 256;    // 64
constexpr int PRE_H0   = 2 * WC_BLKS;            // 128 (hist chunks start)
constexpr int PRE_BLKS = PRE_H0 + NCHUNK;        // 519

constexpr int GB1 = (N + 63) / 64;               // 782 gemm blocks
constexpr int AGB = N / 16;                      // 3125 fused agg+gemm blocks

typedef __attribute__((ext_vector_type(8))) short short8;
typedef __attribute__((ext_vector_type(4))) float floatx4;

// bf16 <-> fp32 helpers (RNE on pack; values are finite)
__device__ inline float bf2f(unsigned short u) {
    union { unsigned int i; float f; } v;
    v.i = ((unsigned int)u) << 16;
    return v.f;
}
__device__ inline unsigned short f2bf(float f) {
    union { float f; unsigned int i; } v;
    v.f = f;
    unsigned int r = v.i + 0x7FFF + ((v.i >> 16) & 1);
    return (unsigned short)(r >> 16);
}
__device__ inline unsigned int pack2bf(float a, float b) {
    return (unsigned int)f2bf(a) | ((unsigned int)f2bf(b) << 16);
}

// pack W (fp32) -> MFMA-B-fragment order, hi/lo bf16 split
__device__ inline void wcast_one(const float* __restrict__ W,
                                 unsigned short* __restrict__ Whi,
                                 unsigned short* __restrict__ Wlo, int i) {
    if (i >= F * F) return;
    int k = i >> 7, n = i & 127;
    float w = W[i];
    unsigned short hi = f2bf(w);
    unsigned short lo = f2bf(w - bf2f(hi));
    int s = k >> 5, q = (k >> 3) & 3, j = k & 7;
    int idx = (((s * 128 + n) * 4 + q) * 8) + j;
    Whi[idx] = hi;
    Wlo[idx] = lo;
}

// ---------------- fused preamble: wcast(W1/W2) + per-chunk LDS bucket histogram ----------
__global__ __launch_bounds__(256) void k_pre(const float* __restrict__ W1, const float* __restrict__ W2,
                                             unsigned short* __restrict__ w1h, unsigned short* __restrict__ w1l,
                                             unsigned short* __restrict__ w2h, unsigned short* __restrict__ w2l,
                                             const int* __restrict__ dst, int* __restrict__ cnts) {
    __shared__ int h[NBUCK];
    int b = blockIdx.x, t = threadIdx.x;
    if (b < WC_BLKS) {
        wcast_one(W1, w1h, w1l, b * 256 + t);
    } else if (b < 2 * WC_BLKS) {
        wcast_one(W2, w2h, w2l, (b - WC_BLKS) * 256 + t);
    } else {
        int chunk = b - PRE_H0;
        for (int i = t; i < NBUCK; i += 256) h[i] = 0;
        __syncthreads();
        int base = chunk * CHUNK;
        for (int i = t; i < CHUNK; i += 256) {
            int e = base + i;
            if (e < E) atomicAdd(&h[dst[e] >> BSH], 1);   // LDS atomic
        }
        __syncthreads();
        for (int i = t; i < NBUCK; i += 256) cnts[chunk * NBUCK + i] = h[i];
    }
}

// ---------------- per-bucket scan over chunks: cnts -> within-bucket offsets + totals --------
__global__ __launch_bounds__(256) void k_colscan(int* __restrict__ cnts, int* __restrict__ btot) {
    int j = blockIdx.x * 256 + threadIdx.x;
    if (j >= NBUCK) return;
    int run = 0;
    for (int k = 0; k < NCHUNK; ++k) {
        int v = cnts[k * NBUCK + j];
        cnts[k * NBUCK + j] = run;
        run += v;
    }
    btot[j] = run;
}

// ---------------- scan bucket totals -> bucketbase (exclusive) ----------------
__global__ __launch_bounds__(256) void k_bucketscan(const int* __restrict__ btot,
                                                    int* __restrict__ bucketbase) {
    __shared__ int part[256];
    int t = threadIdx.x;
    constexpr int CH = (NBUCK + 255) / 256;   // 7
    int beg = t * CH;
    int end = (beg + CH < NBUCK) ? beg + CH : NBUCK;
    int tot[CH];
    int s = 0;
    for (int i = beg; i < end; ++i) {
        tot[i - beg] = btot[i];
        s += btot[i];
    }
    part[t] = s;
    __syncthreads();
    for (int off = 1; off < 256; off <<= 1) {
        int u = (t >= off) ? part[t - off] : 0;
        __syncthreads();
        part[t] += u;
        __syncthreads();
    }
    int run = (t == 0) ? 0 : part[t - 1];
    for (int i = beg; i < end; ++i) {
        bucketbase[i] = run;
        run += tot[i - beg];
    }
    if (t == 255) bucketbase[NBUCK] = part[255];  // == E
}

// ---------------- deterministic partition: edges -> bucket-contiguous staging (4B packed) ----
__global__ __launch_bounds__(256) void k_fillb(const int* __restrict__ src,
                                               const int* __restrict__ dst,
                                               const int* __restrict__ cnts,
                                               const int* __restrict__ bucketbase,
                                               unsigned int* __restrict__ staging) {
    __shared__ int lofs[NBUCK];
    int chunk = blockIdx.x, t = threadIdx.x;
    for (int i = t; i < NBUCK; i += 256)
        lofs[i] = bucketbase[i] + cnts[chunk * NBUCK + i];
    __syncthreads();
    int base = chunk * CHUNK;
    for (int i = t; i < CHUNK; i += 256) {
        int e = base + i;
        if (e < E) {
            int d = dst[e];
            int pos = atomicAdd(&lofs[d >> BSH], 1);      // LDS atomic
            staging[pos] = (unsigned int)src[e] | ((unsigned int)(d & (BNODES - 1)) << 16);
        }
    }
}

// ---------------- pass B: per-bucket counting sort by (dstLow5, srcSlice) ------------------
__global__ __launch_bounds__(256) void k_passB(const unsigned int* __restrict__ staging,
                                               const int* __restrict__ bucketbase,
                                               int* __restrict__ csr,
                                               int* __restrict__ rowstart,
                                               float* __restrict__ dinv) {
    __shared__ unsigned int ent[1024];        // mean 512, 11-sigma safe
    __shared__ int h[BNODES * 8], off_a[BNODES * 8];   // (node, slice) bins
    __shared__ int nodebase[BNODES], ndeg[BNODES];
    int b = blockIdx.x, t = threadIdx.x;
    int jb = bucketbase[b], je = bucketbase[b + 1];
    int M = je - jb;
    if (M > 1024) M = 1024;
    if (t < BNODES * 8) h[t] = 0;
    __syncthreads();

    for (int i = t; i < M; i += 256) {
        unsigned int en = staging[jb + i];
        ent[i] = en;
        int key = (((en >> 16) & (BNODES - 1)) << 3) | ((en & 0xFFFFu) >> SSH);
        atomicAdd(&h[key], 1);
    }
    __syncthreads();

    if (t < BNODES) {
        int s = 0;
#pragma unroll
        for (int c = 0; c < 8; ++c) s += h[t * 8 + c];
        ndeg[t] = s;
    }
    __syncthreads();
    if (t == 0) {
        int run = jb;
        for (int k = 0; k < BNODES; ++k) {
            nodebase[k] = run;
            run += ndeg[k];
        }
    }
    __syncthreads();
    if (t < BNODES) {
        int run = nodebase[t];
#pragma unroll
        for (int c = 0; c < 8; ++c) {
            off_a[t * 8 + c] = run;
            run += h[t * 8 + c];
        }
        int node = b * BNODES + t;
        if (node < N) {
            rowstart[node] = nodebase[t];
            dinv[node] = rsqrtf((float)(ndeg[t] + 1));   // +1 self-loop
        }
    }
    if (b == 0 && t == 0) rowstart[N] = E;
    __syncthreads();

    for (int i = t; i < M; i += 256) {
        unsigned int en = ent[i];
        int key = (((en >> 16) & (BNODES - 1)) << 3) | ((en & 0xFFFFu) >> SSH);
        int loc = atomicAdd(&off_a[key], 1);
        csr[loc] = (int)(en & 0xFFFFu);
    }
}

// ---------------- MFMA GEMM body (64-row tile): C16 = dinv[row] * (A @ W) ----------------
template <bool ABF16>
__device__ __forceinline__ void gemm_body(const void* __restrict__ Ain,
                                          const unsigned short* __restrict__ Wph,
                                          const unsigned short* __restrict__ Wpl,
                                          const float* __restrict__ dinv,
                                          unsigned short* __restrict__ C16,
                                          int row0, int tid) {
    __shared__ __align__(16) unsigned short Albs[64 * 136];  // row-major, pad 136

    if (ABF16) {
        const uint4* A8 = (const uint4*)Ain;
        for (int f = tid; f < 64 * 16; f += 256) {
            int r = f >> 4, kq = f & 15;
            int row = row0 + r;
            uint4 v = make_uint4(0u, 0u, 0u, 0u);
            if (row < N) v = A8[row * 16 + kq];
            *(uint4*)&Albs[r * 136 + kq * 8] = v;
        }
    } else {
        const float4* A4 = (const float4*)Ain;
        for (int f = tid; f < 64 * 32; f += 256) {
            int r = f >> 5, kq = f & 31;
            int row = row0 + r;
            float4 v = make_float4(0.f, 0.f, 0.f, 0.f);
            if (row < N) v = A4[row * 32 + kq];
            ushort4 o;
            o.x = f2bf(v.x); o.y = f2bf(v.y); o.z = f2bf(v.z); o.w = f2bf(v.w);
            *(ushort4*)&Albs[r * 136 + kq * 4] = o;
        }
    }
    __syncthreads();

    int wv = tid >> 6;
    int lane = tid & 63;
    int c16 = lane & 15;
    int q = lane >> 4;
    int m = wv * 16 + c16;

    floatx4 acc[8];
#pragma unroll
    for (int nt = 0; nt < 8; ++nt) acc[nt] = (floatx4){0.f, 0.f, 0.f, 0.f};

    const short8* WH = (const short8*)Wph;
    const short8* WL = (const short8*)Wpl;
#pragma unroll
    for (int s = 0; s < 4; ++s) {
        short8 a = *(const short8*)&Albs[m * 136 + s * 32 + q * 8];
        int wb = s * 512 + c16 * 4 + q;
#pragma unroll
        for (int nt = 0; nt < 8; ++nt) {
            acc[nt] = __builtin_amdgcn_mfma_f32_16x16x32_bf16(a, WH[wb + nt * 64], acc[nt], 0, 0, 0);
            acc[nt] = __builtin_amdgcn_mfma_f32_16x16x32_bf16(a, WL[wb + nt * 64], acc[nt], 0, 0, 0);
        }
    }

    int rbase = row0 + wv * 16 + q * 4;
#pragma unroll
    for (int r = 0; r < 4; ++r) {
        int row = rbase + r;
        if (row < N) {
            float dv = dinv[row];
#pragma unroll
            for (int nt = 0; nt < 8; ++nt)
                C16[row * 128 + nt * 16 + c16] = f2bf(acc[nt][r] * dv);
        }
    }
}

template <bool ABF16>
__global__ __launch_bounds__(256) void k_gemm(const void* __restrict__ Ain,
                                              const unsigned short* __restrict__ Wph,
                                              const unsigned short* __restrict__ Wpl,
                                              const float* __restrict__ dinv,
                                              unsigned short* __restrict__ C16) {
    gemm_body<ABF16>(Ain, Wph, Wpl, dinv, C16, blockIdx.x * 64, threadIdx.x);
}

// 8 bf16 (uint4) fma into 8 fp32 accumulators
__device__ inline void fma8(const uint4& u, float c, float* acc) {
    union { unsigned int i; float f; } a;
    a.i = u.x << 16;          acc[0] = fmaf(a.f, c, acc[0]);
    a.i = u.x & 0xFFFF0000u;  acc[1] = fmaf(a.f, c, acc[1]);
    a.i = u.y << 16;          acc[2] = fmaf(a.f, c, acc[2]);
    a.i = u.y & 0xFFFF0000u;  acc[3] = fmaf(a.f, c, acc[3]);
    a.i = u.z << 16;          acc[4] = fmaf(a.f, c, acc[4]);
    a.i = u.z & 0xFFFF0000u;  acc[5] = fmaf(a.f, c, acc[5]);
    a.i = u.w << 16;          acc[6] = fmaf(a.f, c, acc[6]);
    a.i = u.w & 0xFFFF0000u;  acc[7] = fmaf(a.f, c, acc[7]);
}

// agg inner loop: acc += Sum_{j in [jb,je)} tmp[csr[j]] (8-deep in flight)
__device__ __forceinline__ void agg_loop(const uint4* __restrict__ t8,
                                         const int* __restrict__ csr,
                                         int jb, int je, int lane, float* acc) {
    for (int j = jb; j < je; j += 8) {
        int e[8];
        float msk[8];
#pragma unroll
        for (int k = 0; k < 8; ++k) {
            int idx = j + k;
            e[k] = csr[idx < je ? idx : je - 1];
            msk[k] = (idx < je) ? 1.0f : 0.0f;
        }
        uint4 u[8];
#pragma unroll
        for (int k = 0; k < 8; ++k) u[k] = t8[e[k] * 16 + lane];
#pragma unroll
        for (int k = 0; k < 8; ++k) fma8(u[k], msk[k], acc);
    }
}

// ---------------- fused layer-1 agg + layer-2 GEMM (16 nodes/block) ----------------
__global__ __launch_bounds__(256) void k_agg1gemm(const unsigned short* __restrict__ tmp16,
                                                  const int* __restrict__ csr,
                                                  const int* __restrict__ rowstart,
                                                  const float* __restrict__ dinv,
                                                  const float* __restrict__ bias,
                                                  const unsigned short* __restrict__ w2h,
                                                  const unsigned short* __restrict__ w2l,
                                                  unsigned short* __restrict__ tmp2) {
    __shared__ __align__(16) unsigned short Albs[16 * 136];
    int tid = threadIdx.x;
    int row0 = blockIdx.x * 16;

    // ---- phase A: aggregation ----
    {
        int node = row0 + (tid >> 4);
        int lane = tid & 15;
        const uint4* t8 = (const uint4*)tmp16;
        float acc[8] = {0.f, 0.f, 0.f, 0.f, 0.f, 0.f, 0.f, 0.f};
        fma8(t8[node * 16 + lane], 1.0f, acc);
        agg_loop(t8, csr, rowstart[node], rowstart[node + 1], lane, acc);

        float di = dinv[node];
        const float4* b4 = (const float4*)bias;
        float4 ba = b4[lane * 2], bb = b4[lane * 2 + 1];
        uint4 o;
        o.x = pack2bf(fmaxf(fmaf(acc[0], di, ba.x), 0.f), fmaxf(fmaf(acc[1], di, ba.y), 0.f));
        o.y = pack2bf(fmaxf(fmaf(acc[2], di, ba.z), 0.f), fmaxf(fmaf(acc[3], di, ba.w), 0.f));
        o.z = pack2bf(fmaxf(fmaf(acc[4], di, bb.x), 0.f), fmaxf(fmaf(acc[5], di, bb.y), 0.f));
        o.w = pack2bf(fmaxf(fmaf(acc[6], di, bb.z), 0.f), fmaxf(fmaf(acc[7], di, bb.w), 0.f));
        *(uint4*)&Albs[(tid >> 4) * 136 + lane * 8] = o;
    }
    __syncthreads();

    // ---- phase B: 16-row MFMA gemm, 4 waves x 2 n-tiles ----
    int wv = tid >> 6;
    int lane = tid & 63;
    int c16 = lane & 15;
    int q = lane >> 4;

    floatx4 acc[2];
    acc[0] = (floatx4){0.f, 0.f, 0.f, 0.f};
    acc[1] = (floatx4){0.f, 0.f, 0.f, 0.f};

    const short8* WH = (const short8*)w2h;
    const short8* WL = (const short8*)w2l;
#pragma unroll
    for (int s = 0; s < 4; ++s) {
        short8 a = *(const short8*)&Albs[c16 * 136 + s * 32 + q * 8];
        int wb = s * 512 + c16 * 4 + q;
#pragma unroll
        for (int i = 0; i < 2; ++i) {
            int nt = wv * 2 + i;
            acc[i] = __builtin_amdgcn_mfma_f32_16x16x32_bf16(a, WH[wb + nt * 64], acc[i], 0, 0, 0);
            acc[i] = __builtin_amdgcn_mfma_f32_16x16x32_bf16(a, WL[wb + nt * 64], acc[i], 0, 0, 0);
        }
    }

    int rbase = row0 + q * 4;
#pragma unroll
    for (int r = 0; r < 4; ++r) {
        int row = rbase + r;
        float dv = dinv[row];
#pragma unroll
        for (int i = 0; i < 2; ++i) {
            int nt = wv * 2 + i;
            tmp2[row * 128 + nt * 16 + c16] = f2bf(acc[i][r] * dv);
        }
    }
}

// ---------------- layer-2 aggregation (standalone) ----------------
__global__ __launch_bounds__(256) void k_agg(const unsigned short* __restrict__ tmp16,
                                             const int* __restrict__ csr,
                                             const int* __restrict__ rowstart,
                                             const float* __restrict__ dinv,
                                             const float* __restrict__ bias,
                                             unsigned short* __restrict__ out16) {
    int node = (blockIdx.x * blockDim.x + threadIdx.x) >> 4;
    int lane = threadIdx.x & 15;
    if (node >= N) return;
    const uint4* t8 = (const uint4*)tmp16;
    float acc[8] = {0.f, 0.f, 0.f, 0.f, 0.f, 0.f, 0.f, 0.f};
    fma8(t8[node * 16 + lane], 1.0f, acc);
    agg_loop(t8, csr, rowstart[node], rowstart[node + 1], lane, acc);

    float di = dinv[node];
    const float4* b4 = (const float4*)bias;
    float4 ba = b4[lane * 2], bb = b4[lane * 2 + 1];
    uint4 o;
    o.x = pack2bf(fmaxf(fmaf(acc[0], di, ba.x), 0.f), fmaxf(fmaf(acc[1], di, ba.y), 0.f));
    o.y = pack2bf(fmaxf(fmaf(acc[2], di, ba.z), 0.f), fmaxf(fmaf(acc[3], di, ba.w), 0.f));
    o.z = pack2bf(fmaxf(fmaf(acc[4], di, bb.x), 0.f), fmaxf(fmaf(acc[5], di, bb.y), 0.f));
    o.w = pack2bf(fmaxf(fmaf(acc[6], di, bb.z), 0.f), fmaxf(fmaf(acc[7], di, bb.w), 0.f));
    ((uint4*)out16)[node * 16 + lane] = o;
}

// ---------------- fused pool + fc + head: one block per graph, zero atomics ----------------
__global__ __launch_bounds__(256) void k_poolhead(const unsigned short* __restrict__ h16,
                                                  const int* __restrict__ batch,
                                                  const float* __restrict__ Wfc,
                                                  const float* __restrict__ bfc,
                                                  const float* __restrict__ Wh,
                                                  const float* __restrict__ bh,
                                                  float* __restrict__ out) {
    __shared__ float red[16][128];            // 8 KB
    __shared__ float p[128];
    __shared__ float zs[128];
    int g = blockIdx.x, t = threadIdx.x;
    int rg = t >> 4, lane = t & 15;

    int lo = 0, hi = N;                       // lower_bound(g)
    while (lo < hi) { int m = (lo + hi) >> 1; if (batch[m] < g) lo = m + 1; else hi = m; }
    int lo1 = lo, hi1 = N;                    // lower_bound(g+1)
    while (lo1 < hi1) { int m = (lo1 + hi1) >> 1; if (batch[m] < g + 1) lo1 = m + 1; else hi1 = m; }
    int cnt = lo1 - lo;

    float acc[8] = {0.f, 0.f, 0.f, 0.f, 0.f, 0.f, 0.f, 0.f};
    const uint4* h4 = (const uint4*)h16;
    for (int i = lo + rg; i < lo1; i += 16)
        fma8(h4[i * 16 + lane], 1.0f, acc);
#pragma unroll
    for (int k = 0; k < 8; ++k) red[rg][lane * 8 + k] = acc[k];
    __syncthreads();

    if (t < 128) {
        float s = 0.f;
#pragma unroll
        for (int r = 0; r < 16; ++r) s += red[r][t];
        p[t] = s / (float)((cnt > 1) ? cnt : 1);
    }
    __syncthreads();

    if (t < 128) {
        float a = bfc[t];
        for (int k = 0; k < F; ++k) a = fmaf(p[k], Wfc[k * F + t], a);
        zs[t] = fmaxf(a, 0.f);
    }
    __syncthreads();

    if (t < T * 2) {
        int task = t >> 1, c = t & 1;
        float a = bh[task * 2 + c];
        const float* wr = &Wh[task * F * 2 + c];
        for (int h = 0; h < F; ++h) a = fmaf(zs[h], wr[h * 2], a);
        out[task * (G * 2) + g * 2 + c] = a;
    }
}

extern "C" void kernel_launch(void* const* d_in, const int* in_sizes, int n_in,
                              void* d_out, int out_size, void* d_ws, size_t ws_size,
                              hipStream_t stream) {
    const float* x    = (const float*)d_in[0];
    const int*   ei   = (const int*)d_in[1];      // [2,E]: row0=src, row1=dst
    const int*   batch= (const int*)d_in[2];
    const float* W1   = (const float*)d_in[3];
    const float* b1   = (const float*)d_in[4];
    const float* W2   = (const float*)d_in[5];
    const float* b2   = (const float*)d_in[6];
    const float* Wfc  = (const float*)d_in[7];
    const float* bfc  = (const float*)d_in[8];
    const float* Wh   = (const float*)d_in[9];
    const float* bh   = (const float*)d_in[10];
    float* out = (float*)d_out;

    const int* srcp = ei;
    const int* dstp = ei + E;

    char* w = (char*)d_ws;
    auto alloc = [&](size_t bytes) {
        char* p = w;
        w += (bytes + 255) & ~(size_t)255;
        return p;
    };
    unsigned short* tmp16 = (unsigned short*)alloc((size_t)N * F * 2);
    unsigned short* tmp2  = (unsigned short*)alloc((size_t)N * F * 2);
    unsigned short* hbuf16= (unsigned short*)alloc((size_t)N * F * 2);
    int*   csr      = (int*)  alloc((size_t)E * 4);
    unsigned int* staging = (unsigned int*)alloc((size_t)E * 4);
    int*   cnts     = (int*)  alloc((size_t)NCHUNK * NBUCK * 4);
    int*   btot     = (int*)  alloc((size_t)NBUCK * 4);
    int*   bucketbase=(int*)  alloc((size_t)(NBUCK + 1) * 4);
    int*   rowstart = (int*)  alloc((size_t)(N + 1) * 4);
    float* dinv     = (float*)alloc((size_t)N * 4);
    unsigned short* w1h = (unsigned short*)alloc((size_t)F * F * 2);
    unsigned short* w1l = (unsigned short*)alloc((size_t)F * F * 2);
    unsigned short* w2h = (unsigned short*)alloc((size_t)F * F * 2);
    unsigned short* w2l = (unsigned short*)alloc((size_t)F * F * 2);

    // fused preamble: wcast W1/W2 + per-chunk LDS bucket histogram
    k_pre<<<PRE_BLKS, 256, 0, stream>>>(W1, W2, w1h, w1l, w2h, w2l, dstp, cnts);

    // deterministic radix partition (zero global atomics); csr sorted by src-slice per node
    k_colscan<<<(NBUCK + 255) / 256, 256, 0, stream>>>(cnts, btot);
    k_bucketscan<<<1, 256, 0, stream>>>(btot, bucketbase);
    k_fillb<<<NCHUNK, 256, 0, stream>>>(srcp, dstp, cnts, bucketbase, staging);
    k_passB<<<NBUCK, 256, 0, stream>>>(staging, bucketbase, csr, rowstart, dinv);

    // layer-1 GEMM (dinv-prescaled output)
    k_gemm<false><<<GB1, 256, 0, stream>>>(x, w1h, w1l, dinv, tmp16);

    // fused: layer-1 aggregation + layer-2 GEMM (h1 stays in LDS)
    k_agg1gemm<<<AGB, 256, 0, stream>>>(tmp16, csr, rowstart, dinv, b1, w2h, w2l, tmp2);

    // layer-2 aggregation
    k_agg<<<(N * 16 + 255) / 256, 256, 0, stream>>>(tmp2, csr, rowstart, dinv, b2, hbuf16);

    // fused pool + fc + head: one block per graph
    k_poolhead<<<G, 256, 0, stream>>>(hbuf16, batch, Wfc, bfc, Wh, bh, out);
}